// Round 2
// baseline (344.251 us; speedup 1.0000x reference)
//
#include <hip/hip_runtime.h>
#include <hip/hip_bf16.h>

// Problem constants
#define B_SZ 256
#define SDIM 1024
#define ADIM 512

#define BK 32
#define NSTEPS (SDIM / BK)

typedef __attribute__((ext_vector_type(8))) short bf16x8;
typedef __attribute__((ext_vector_type(4))) float f32x4;

__device__ __forceinline__ unsigned short f2bf(float x) {
  union { float f; unsigned u; } v; v.f = x;
  unsigned r = v.u + 0x7FFFu + ((v.u >> 16) & 1u);   // round-to-nearest-even
  return (unsigned short)(r >> 16);
}

// ---------------- Kernel 1: small MLPs + obs->bf16 staging ----------------
__global__ __launch_bounds__(128) void kprep(
    const float* __restrict__ obs,
    const float* __restrict__ task, const int* __restrict__ action,
    const float* __restrict__ we1, const float* __restrict__ be1,
    const float* __restrict__ we2, const float* __restrict__ be2,
    const float* __restrict__ aw1, const float* __restrict__ aw1b,
    const float* __restrict__ ab1, const float* __restrict__ ab1b,
    const float* __restrict__ ab2, const float* __restrict__ ab2b,
    const float* __restrict__ cw1, const float* __restrict__ cw1b,
    const float* __restrict__ cb1, const float* __restrict__ cb1b,
    const float* __restrict__ cb2, const float* __restrict__ cb2b,
    float* __restrict__ ws_ha, float* __restrict__ ws_hc,
    unsigned short* __restrict__ ws_obs,
    float* __restrict__ out)
{
  const int b = blockIdx.x, t = threadIdx.x;
  __shared__ float s_task[64], s_t1[64], s_z[64], s_hb[128], s_red[128];

  // obs row b -> bf16 into ws_obs
  {
    const float4* orow = (const float4*)(obs + (size_t)b * SDIM);
    ushort4* wrow = (ushort4*)(ws_obs + (size_t)b * SDIM);
#pragma unroll
    for (int i = 0; i < 2; ++i) {
      const int idx = t + i * 128;
      float4 v = orow[idx];
      ushort4 u;
      u.x = f2bf(v.x); u.y = f2bf(v.y); u.z = f2bf(v.z); u.w = f2bf(v.w);
      wrow[idx] = u;
    }
  }

  if (t < 64) s_task[t] = task[b * 64 + t];
  __syncthreads();
  if (t < 64) {
    float a = be1[t];
    for (int e = 0; e < 64; ++e) a += s_task[e] * we1[e * 64 + t];
    s_t1[t] = fmaxf(a, 0.0f);
  }
  __syncthreads();
  if (t < 64) {
    float a = be2[t];
    for (int e = 0; e < 64; ++e) a += s_t1[e] * we2[e * 64 + t];
    s_z[t] = fmaxf(a, 0.0f);
  }
  __syncthreads();
  {
    float a1 = aw1b[t], a2 = ab1b[t], a3 = cw1b[t], a4 = cb1b[t];
    for (int e = 0; e < 64; ++e) {
      const float zv = s_z[e];
      a1 += zv * aw1[e * 128 + t];
      a2 += zv * ab1[e * 128 + t];
      a3 += zv * cw1[e * 128 + t];
      a4 += zv * cb1[e * 128 + t];
    }
    ws_ha[b * 128 + t] = fmaxf(a1, 0.0f);
    s_hb[t] = fmaxf(a2, 0.0f);
    ws_hc[b * 128 + t] = fmaxf(a3, 0.0f);
    s_red[t] = fmaxf(a4, 0.0f) * cb2[t];   // cb2 is [128,1]
  }
  __syncthreads();
  // ba -> staged into d_out logits slots (khyper accumulates on top)
  for (int o = t; o < ADIM; o += 128) {
    float a = ab2b[o];
    for (int h = 0; h < 128; ++h) a += s_hb[h] * ab2[h * ADIM + o];
    out[b * ADIM + o] = a;
  }
  // bv reduction
  for (int s = 64; s > 0; s >>= 1) {
    __syncthreads();
    if (t < s) s_red[t] += s_red[t + s];
  }
  if (t == 0) {
    out[131840 + b] = s_red[0] + cb2b[0];      // partial v (bv); critic block adds rest
    out[131072 + b] = (float)action[b];        // action as float
  }
}

// ---------------- Kernel 2: hypernet heavy GEMM + h-reduction ----------------
// No LDS staging, no K-loop barriers: both MFMA operands loaded directly from
// global in fragment layout; B (f32) double-buffered in registers.
__global__ __launch_bounds__(512, 2) void khyper(
    const unsigned short* __restrict__ ws_obs,
    const float* __restrict__ aw2, const float* __restrict__ aw2b,
    const float* __restrict__ cw2, const float* __restrict__ cw2b,
    const float* __restrict__ ws_ha, const float* __restrict__ ws_hc,
    float* __restrict__ d_out)
{
  __shared__ float logits_buf[B_SZ];

  const int tid = threadIdx.x;
  const int blk = blockIdx.x;
  const bool critic = (blk == 0);           // block 0 = critic (starts first, no tail)
  const int o = critic ? 0 : (blk - 1);
  const float* haW = critic ? ws_hc : ws_ha;

  const int lane = tid & 63;
  const int wv = tid >> 6;
  const int mbase = (wv & 3) * 64;    // 4 wave-groups over M=256
  const int nbase = (wv >> 2) * 80;   // 2 wave-groups over N=160 (128 h + bias + pad)
  const int lrow = lane & 15;
  const int lk8 = (lane >> 4) * 8;

  // Per-lane fragment base pointers
  const unsigned short* pA[4];
#pragma unroll
  for (int mf = 0; mf < 4; ++mf) {
    const int rowm = mbase + mf * 16 + lrow;
    pA[mf] = ws_obs + (size_t)rowm * SDIM + lk8;
  }
  const float* pB[5];
#pragma unroll
  for (int nf = 0; nf < 5; ++nf) {
    const int h = nbase + nf * 16 + lrow;
    const float* base;
    if (critic) base = (h < 128) ? (cw2 + (size_t)h * SDIM) : cw2b;
    else        base = (h < 128) ? (aw2 + (size_t)h * (ADIM * SDIM) + (size_t)o * SDIM)
                                 : (aw2b + (size_t)o * SDIM);
    pB[nf] = base + lk8;
  }

  f32x4 acc[4][5];
#pragma unroll
  for (int mf = 0; mf < 4; ++mf)
#pragma unroll
    for (int nf = 0; nf < 5; ++nf) acc[mf][nf] = (f32x4)(0.0f);

#define LOADB(BUF, T)                                                   \
  {                                                                     \
    const size_t k0_ = (size_t)(T) * BK;                                \
    _Pragma("unroll")                                                   \
    for (int nf = 0; nf < 5; ++nf) {                                    \
      BUF[nf][0] = *(const float4*)(pB[nf] + k0_);                      \
      BUF[nf][1] = *(const float4*)(pB[nf] + k0_ + 4);                  \
    }                                                                   \
  }

#define COMPUTE(BUF, T)                                                 \
  {                                                                     \
    const size_t k0_ = (size_t)(T) * BK;                                \
    bf16x8 af[4];                                                       \
    _Pragma("unroll")                                                   \
    for (int mf = 0; mf < 4; ++mf)                                      \
      af[mf] = *(const bf16x8*)(pA[mf] + k0_);                          \
    bf16x8 bfr[5];                                                      \
    _Pragma("unroll")                                                   \
    for (int nf = 0; nf < 5; ++nf) {                                    \
      bf16x8 v;                                                         \
      v[0] = (short)f2bf(BUF[nf][0].x); v[1] = (short)f2bf(BUF[nf][0].y); \
      v[2] = (short)f2bf(BUF[nf][0].z); v[3] = (short)f2bf(BUF[nf][0].w); \
      v[4] = (short)f2bf(BUF[nf][1].x); v[5] = (short)f2bf(BUF[nf][1].y); \
      v[6] = (short)f2bf(BUF[nf][1].z); v[7] = (short)f2bf(BUF[nf][1].w); \
      bfr[nf] = v;                                                      \
    }                                                                   \
    _Pragma("unroll")                                                   \
    for (int mf = 0; mf < 4; ++mf)                                      \
      _Pragma("unroll")                                                 \
      for (int nf = 0; nf < 5; ++nf)                                    \
        acc[mf][nf] = __builtin_amdgcn_mfma_f32_16x16x32_bf16(af[mf], bfr[nf], acc[mf][nf], 0, 0, 0); \
  }

  float4 b0[5][2], b1[5][2];
  LOADB(b0, 0);
#pragma unroll 1
  for (int t = 0; t < NSTEPS; t += 2) {
    LOADB(b1, t + 1);          // in flight across compute of b0
    COMPUTE(b0, t);
    if (t + 2 < NSTEPS) LOADB(b0, t + 2);   // in flight across compute of b1
    COMPUTE(b1, t + 1);
  }
#undef LOADB
#undef COMPUTE

  // Epilogue: logits[b] = sum_h weight(h) * G[b,h]
  if (tid < B_SZ) logits_buf[tid] = 0.0f;
  __syncthreads();

  float val[4][4];
#pragma unroll
  for (int mf = 0; mf < 4; ++mf)
#pragma unroll
    for (int r = 0; r < 4; ++r) val[mf][r] = 0.0f;

#pragma unroll
  for (int nf = 0; nf < 5; ++nf) {
    const int hidx = nbase + nf * 16 + lrow;
    if (hidx < 128) {
#pragma unroll
      for (int mf = 0; mf < 4; ++mf) {
        const int m0 = mbase + mf * 16 + ((lane >> 4) << 2);
#pragma unroll
        for (int r = 0; r < 4; ++r)
          val[mf][r] += haW[(m0 + r) * 128 + hidx] * acc[mf][nf][r];
      }
    } else if (hidx == 128) {   // bias row: weight 1
#pragma unroll
      for (int mf = 0; mf < 4; ++mf)
#pragma unroll
        for (int r = 0; r < 4; ++r) val[mf][r] += acc[mf][nf][r];
    }
  }

#pragma unroll
  for (int mf = 0; mf < 4; ++mf)
#pragma unroll
    for (int r = 0; r < 4; ++r) {
      float v = val[mf][r];
      v += __shfl_xor(v, 1, 64);
      v += __shfl_xor(v, 2, 64);
      v += __shfl_xor(v, 4, 64);
      v += __shfl_xor(v, 8, 64);
      val[mf][r] = v;
    }
  if ((lane & 15) == 0) {
#pragma unroll
    for (int mf = 0; mf < 4; ++mf)
#pragma unroll
      for (int r = 0; r < 4; ++r)
        atomicAdd(&logits_buf[mbase + mf * 16 + ((lane >> 4) << 2) + r], val[mf][r]);
  }
  __syncthreads();

  if (tid < B_SZ) {
    if (!critic) {
      float* p = d_out + (size_t)tid * ADIM + o;   // ba pre-staged by kprep
      *p += logits_buf[tid];
    } else {
      d_out[131840 + tid] += logits_buf[tid];      // v = bv(partial) + sum_h hc*G
    }
  }
}

// ---------------- Kernel 3: log_softmax / entropy / log_prob ----------------
__global__ __launch_bounds__(256) void kfinal(const int* __restrict__ action,
                                              float* __restrict__ d_out)
{
  const int b = blockIdx.x, t = threadIdx.x;
  const float* lrow = d_out + (size_t)b * ADIM;
  __shared__ float sM[4], sS[4], sT[4];

  const float x0 = lrow[t], x1 = lrow[t + 256];
  float m = fmaxf(x0, x1);
#pragma unroll
  for (int s = 1; s < 64; s <<= 1) m = fmaxf(m, __shfl_xor(m, s, 64));
  const int wv = t >> 6, ln = t & 63;
  if (ln == 0) sM[wv] = m;
  __syncthreads();
  m = fmaxf(fmaxf(sM[0], sM[1]), fmaxf(sM[2], sM[3]));

  const float d0 = x0 - m, d1 = x1 - m;
  const float e0 = expf(d0), e1 = expf(d1);
  float s1 = e0 + e1;
  float s2 = e0 * d0 + e1 * d1;
#pragma unroll
  for (int s = 1; s < 64; s <<= 1) {
    s1 += __shfl_xor(s1, s, 64);
    s2 += __shfl_xor(s2, s, 64);
  }
  if (ln == 0) { sS[wv] = s1; sT[wv] = s2; }
  __syncthreads();
  if (t == 0) {
    const float S = sS[0] + sS[1] + sS[2] + sS[3];
    const float T = sT[0] + sT[1] + sT[2] + sT[3];
    const float lnS = logf(S);
    const int a = action[b];
    d_out[131328 + b] = (lrow[a] - m) - lnS;   // log_prob
    d_out[131584 + b] = lnS - T / S;           // entropy
  }
}

extern "C" void kernel_launch(void* const* d_in, const int* in_sizes, int n_in,
                              void* d_out_v, int out_size, void* d_ws, size_t ws_size,
                              hipStream_t stream) {
  const float* obs   = (const float*)d_in[0];
  const float* task  = (const float*)d_in[1];
  const int*   action= (const int*)  d_in[2];
  const float* we1   = (const float*)d_in[3];
  const float* be1   = (const float*)d_in[4];
  const float* we2   = (const float*)d_in[5];
  const float* be2   = (const float*)d_in[6];
  const float* aw1   = (const float*)d_in[7];
  const float* aw1b  = (const float*)d_in[8];
  const float* aw2   = (const float*)d_in[9];
  const float* aw2b  = (const float*)d_in[10];
  const float* ab1   = (const float*)d_in[11];
  const float* ab1b  = (const float*)d_in[12];
  const float* ab2   = (const float*)d_in[13];
  const float* ab2b  = (const float*)d_in[14];
  const float* cw1   = (const float*)d_in[15];
  const float* cw1b  = (const float*)d_in[16];
  const float* cw2   = (const float*)d_in[17];
  const float* cw2b  = (const float*)d_in[18];
  const float* cb1   = (const float*)d_in[19];
  const float* cb1b  = (const float*)d_in[20];
  const float* cb2   = (const float*)d_in[21];
  const float* cb2b  = (const float*)d_in[22];
  float* out = (float*)d_out_v;
  float* ws_ha = (float*)d_ws;                       // [256][128] f32
  float* ws_hc = ws_ha + 256 * 128;                  // [256][128] f32
  unsigned short* ws_obs = (unsigned short*)(ws_hc + 256 * 128);  // [256][1024] bf16

  kprep<<<256, 128, 0, stream>>>(obs, task, action, we1, be1, we2, be2, aw1, aw1b,
                                 ab1, ab1b, ab2, ab2b, cw1, cw1b, cb1, cb1b,
                                 cb2, cb2b, ws_ha, ws_hc, ws_obs, out);
  khyper<<<513, 512, 0, stream>>>(ws_obs, aw2, aw2b, cw2, cw2b, ws_ha, ws_hc, out);
  kfinal<<<256, 256, 0, stream>>>(action, out);
}

// Round 3
// 237.282 us; speedup vs baseline: 1.4508x; 1.4508x over previous
//
#include <hip/hip_runtime.h>
#include <hip/hip_bf16.h>

// Problem constants
#define B_SZ 256
#define SDIM 1024
#define ADIM 512

// khyper tile
#define BK 256
#define NCHUNK (SDIM / BK)     // 4
#define BN 160                 // 128 h + bias row(128) + 31 zero rows
#define PADB 264               // ushort elems per LDS row (528B: 16B-aligned, 4-bank shift)
#define NSLOT 20               // float4 slots per thread: 160 rows * 64 f4 / 512 thr

typedef __attribute__((ext_vector_type(8))) short bf16x8;
typedef __attribute__((ext_vector_type(4))) float f32x4;

__device__ __forceinline__ unsigned short f2bf(float x) {
  union { float f; unsigned u; } v; v.f = x;
  unsigned r = v.u + 0x7FFFu + ((v.u >> 16) & 1u);   // round-to-nearest-even
  return (unsigned short)(r >> 16);
}

// ---------------- Kernel 1: small MLPs + obs->bf16 staging ----------------
__global__ __launch_bounds__(128) void kprep(
    const float* __restrict__ obs,
    const float* __restrict__ task, const int* __restrict__ action,
    const float* __restrict__ we1, const float* __restrict__ be1,
    const float* __restrict__ we2, const float* __restrict__ be2,
    const float* __restrict__ aw1, const float* __restrict__ aw1b,
    const float* __restrict__ ab1, const float* __restrict__ ab1b,
    const float* __restrict__ ab2, const float* __restrict__ ab2b,
    const float* __restrict__ cw1, const float* __restrict__ cw1b,
    const float* __restrict__ cb1, const float* __restrict__ cb1b,
    const float* __restrict__ cb2, const float* __restrict__ cb2b,
    float* __restrict__ ws_ha, float* __restrict__ ws_hc,
    unsigned short* __restrict__ ws_obs,
    float* __restrict__ out)
{
  const int b = blockIdx.x, t = threadIdx.x;
  __shared__ float s_task[64], s_t1[64], s_z[64], s_hb[128], s_red[128];

  // obs row b -> bf16 into ws_obs
  {
    const float4* orow = (const float4*)(obs + (size_t)b * SDIM);
    ushort4* wrow = (ushort4*)(ws_obs + (size_t)b * SDIM);
#pragma unroll
    for (int i = 0; i < 2; ++i) {
      const int idx = t + i * 128;
      float4 v = orow[idx];
      ushort4 u;
      u.x = f2bf(v.x); u.y = f2bf(v.y); u.z = f2bf(v.z); u.w = f2bf(v.w);
      wrow[idx] = u;
    }
  }

  if (t < 64) s_task[t] = task[b * 64 + t];
  __syncthreads();
  if (t < 64) {
    float a = be1[t];
    for (int e = 0; e < 64; ++e) a += s_task[e] * we1[e * 64 + t];
    s_t1[t] = fmaxf(a, 0.0f);
  }
  __syncthreads();
  if (t < 64) {
    float a = be2[t];
    for (int e = 0; e < 64; ++e) a += s_t1[e] * we2[e * 64 + t];
    s_z[t] = fmaxf(a, 0.0f);
  }
  __syncthreads();
  {
    float a1 = aw1b[t], a2 = ab1b[t], a3 = cw1b[t], a4 = cb1b[t];
    for (int e = 0; e < 64; ++e) {
      const float zv = s_z[e];
      a1 += zv * aw1[e * 128 + t];
      a2 += zv * ab1[e * 128 + t];
      a3 += zv * cw1[e * 128 + t];
      a4 += zv * cb1[e * 128 + t];
    }
    ws_ha[b * 128 + t] = fmaxf(a1, 0.0f);
    s_hb[t] = fmaxf(a2, 0.0f);
    ws_hc[b * 128 + t] = fmaxf(a3, 0.0f);
    s_red[t] = fmaxf(a4, 0.0f) * cb2[t];   // cb2 is [128,1]
  }
  __syncthreads();
  // ba -> staged into d_out logits slots (khyper accumulates on top)
  for (int o = t; o < ADIM; o += 128) {
    float a = ab2b[o];
    for (int h = 0; h < 128; ++h) a += s_hb[h] * ab2[h * ADIM + o];
    out[b * ADIM + o] = a;
  }
  // bv reduction
  for (int s = 64; s > 0; s >>= 1) {
    __syncthreads();
    if (t < s) s_red[t] += s_red[t + s];
  }
  if (t == 0) {
    out[131840 + b] = s_red[0] + cb2b[0];      // partial v (bv); critic block adds rest
    out[131072 + b] = (float)action[b];        // action as float
  }
}

// ---------------- Kernel 2: hypernet heavy GEMM + h-reduction ----------------
// BK=256: each wave-load instr reads 1KB contiguous from ONE aw2 row.
// Single-buffer LDS, reg-prefetch of next chunk overlapped with compute.
// Per-block chunk rotation desyncs k-windows across blocks (channel spread).
__global__ __launch_bounds__(512, 2) void khyper(
    const unsigned short* __restrict__ ws_obs,
    const float* __restrict__ aw2, const float* __restrict__ aw2b,
    const float* __restrict__ cw2, const float* __restrict__ cw2b,
    const float* __restrict__ ws_ha, const float* __restrict__ ws_hc,
    float* __restrict__ d_out)
{
  __shared__ unsigned short B_lds[BN * PADB];
  __shared__ float logits_buf[B_SZ];

  const int tid = threadIdx.x;
  const int blk = blockIdx.x;
  const bool critic = (blk == ADIM);          // last block = critic (lone tail)
  const int o = critic ? 0 : blk;
  const float* haW = critic ? ws_hc : ws_ha;

  const float* Wbase = critic ? cw2 : (aw2 + (size_t)o * SDIM);
  const size_t wstride = critic ? (size_t)SDIM : (size_t)ADIM * SDIM;
  const float* Bbias = critic ? cw2b : (aw2b + (size_t)o * SDIM);

  const int lane = tid & 63;
  const int wv = tid >> 6;
  const int mbase = (wv & 3) * 64;    // 4 wave-groups over M=256
  const int nbase = (wv >> 2) * 80;   // 2 wave-groups over N=160
  const int lrow = lane & 15;
  const int lk8 = (lane >> 4) * 8;

  const unsigned short* pA[4];
#pragma unroll
  for (int mf = 0; mf < 4; ++mf)
    pA[mf] = ws_obs + (size_t)(mbase + mf * 16 + lrow) * SDIM + lk8;

  f32x4 acc[4][5];
#pragma unroll
  for (int mf = 0; mf < 4; ++mf)
#pragma unroll
    for (int nf = 0; nf < 5; ++nf) acc[mf][nf] = (f32x4)(0.0f);

  float4 sreg[NSLOT];

  auto LOAD = [&](int c) {
    const int k0 = c * BK;
#pragma unroll
    for (int i = 0; i < NSLOT; ++i) {
      const int f = tid + i * 512;
      const int row = f >> 6, c4 = f & 63;      // 64 float4 per row (BK=256)
      float4 v; v.x = 0.f; v.y = 0.f; v.z = 0.f; v.w = 0.f;
      if (row < 128)       v = *(const float4*)(Wbase + (size_t)row * wstride + c4 * 4 + k0);
      else if (row == 128) v = *(const float4*)(Bbias + c4 * 4 + k0);
      sreg[i] = v;
    }
  };

  auto WRITE = [&]() {
#pragma unroll
    for (int i = 0; i < NSLOT; ++i) {
      const int f = tid + i * 512;
      const int row = f >> 6, c4 = f & 63;
      ushort4 p;
      p.x = f2bf(sreg[i].x); p.y = f2bf(sreg[i].y);
      p.z = f2bf(sreg[i].z); p.w = f2bf(sreg[i].w);
      *(ushort4*)(&B_lds[row * PADB + c4 * 4]) = p;
    }
  };

  auto COMPUTE = [&](int c) {
    const size_t kg = (size_t)c * BK;
#pragma unroll
    for (int kk = 0; kk < BK / 32; ++kk) {
      bf16x8 af[4];
#pragma unroll
      for (int mf = 0; mf < 4; ++mf)
        af[mf] = *(const bf16x8*)(pA[mf] + kg + kk * 32);
      bf16x8 bfr[5];
#pragma unroll
      for (int nf = 0; nf < 5; ++nf)
        bfr[nf] = *(const bf16x8*)(&B_lds[(nbase + nf * 16 + lrow) * PADB + kk * 32 + lk8]);
#pragma unroll
      for (int mf = 0; mf < 4; ++mf)
#pragma unroll
        for (int nf = 0; nf < 5; ++nf)
          acc[mf][nf] = __builtin_amdgcn_mfma_f32_16x16x32_bf16(af[mf], bfr[nf], acc[mf][nf], 0, 0, 0);
    }
  };

  // Per-block rotation of chunk order (valid: acc order-independent)
  const int rot = blk & 3;
  LOAD(rot);
#pragma unroll 1
  for (int c = 0; c < NCHUNK; ++c) {
    const int ce = (c + rot) & 3;
    WRITE();                                   // waits on sreg loads internally
    __syncthreads();                           // LDS writes visible
    if (c + 1 < NCHUNK) LOAD((c + 1 + rot) & 3);  // issue next chunk early
    COMPUTE(ce);
    __syncthreads();                           // all reads done before next WRITE
  }

  // Epilogue: logits[b] = sum_h weight(h) * G[b,h]
  if (tid < B_SZ) logits_buf[tid] = 0.0f;
  __syncthreads();

  float val[4][4];
#pragma unroll
  for (int mf = 0; mf < 4; ++mf)
#pragma unroll
    for (int r = 0; r < 4; ++r) val[mf][r] = 0.0f;

#pragma unroll
  for (int nf = 0; nf < 5; ++nf) {
    const int hidx = nbase + nf * 16 + lrow;
    if (hidx < 128) {
#pragma unroll
      for (int mf = 0; mf < 4; ++mf) {
        const int m0 = mbase + mf * 16 + ((lane >> 4) << 2);
#pragma unroll
        for (int r = 0; r < 4; ++r)
          val[mf][r] += haW[(m0 + r) * 128 + hidx] * acc[mf][nf][r];
      }
    } else if (hidx == 128) {   // bias row: weight 1
#pragma unroll
      for (int mf = 0; mf < 4; ++mf)
#pragma unroll
        for (int r = 0; r < 4; ++r) val[mf][r] += acc[mf][nf][r];
    }
  }

#pragma unroll
  for (int mf = 0; mf < 4; ++mf)
#pragma unroll
    for (int r = 0; r < 4; ++r) {
      float v = val[mf][r];
      v += __shfl_xor(v, 1, 64);
      v += __shfl_xor(v, 2, 64);
      v += __shfl_xor(v, 4, 64);
      v += __shfl_xor(v, 8, 64);
      val[mf][r] = v;
    }
  if ((lane & 15) == 0) {
#pragma unroll
    for (int mf = 0; mf < 4; ++mf)
#pragma unroll
      for (int r = 0; r < 4; ++r)
        atomicAdd(&logits_buf[mbase + mf * 16 + ((lane >> 4) << 2) + r], val[mf][r]);
  }
  __syncthreads();

  if (tid < B_SZ) {
    if (!critic) {
      float* p = d_out + (size_t)tid * ADIM + o;   // ba pre-staged by kprep
      *p += logits_buf[tid];
    } else {
      d_out[131840 + tid] += logits_buf[tid];      // v = bv(partial) + sum_h hc*G
    }
  }
}

// ---------------- Kernel 3: log_softmax / entropy / log_prob ----------------
__global__ __launch_bounds__(256) void kfinal(const int* __restrict__ action,
                                              float* __restrict__ d_out)
{
  const int b = blockIdx.x, t = threadIdx.x;
  const float* lrow = d_out + (size_t)b * ADIM;
  __shared__ float sM[4], sS[4], sT[4];

  const float x0 = lrow[t], x1 = lrow[t + 256];
  float m = fmaxf(x0, x1);
#pragma unroll
  for (int s = 1; s < 64; s <<= 1) m = fmaxf(m, __shfl_xor(m, s, 64));
  const int wv = t >> 6, ln = t & 63;
  if (ln == 0) sM[wv] = m;
  __syncthreads();
  m = fmaxf(fmaxf(sM[0], sM[1]), fmaxf(sM[2], sM[3]));

  const float d0 = x0 - m, d1 = x1 - m;
  const float e0 = expf(d0), e1 = expf(d1);
  float s1 = e0 + e1;
  float s2 = e0 * d0 + e1 * d1;
#pragma unroll
  for (int s = 1; s < 64; s <<= 1) {
    s1 += __shfl_xor(s1, s, 64);
    s2 += __shfl_xor(s2, s, 64);
  }
  if (ln == 0) { sS[wv] = s1; sT[wv] = s2; }
  __syncthreads();
  if (t == 0) {
    const float S = sS[0] + sS[1] + sS[2] + sS[3];
    const float T = sT[0] + sT[1] + sT[2] + sT[3];
    const float lnS = logf(S);
    const int a = action[b];
    d_out[131328 + b] = (lrow[a] - m) - lnS;   // log_prob
    d_out[131584 + b] = lnS - T / S;           // entropy
  }
}

extern "C" void kernel_launch(void* const* d_in, const int* in_sizes, int n_in,
                              void* d_out_v, int out_size, void* d_ws, size_t ws_size,
                              hipStream_t stream) {
  const float* obs   = (const float*)d_in[0];
  const float* task  = (const float*)d_in[1];
  const int*   action= (const int*)  d_in[2];
  const float* we1   = (const float*)d_in[3];
  const float* be1   = (const float*)d_in[4];
  const float* we2   = (const float*)d_in[5];
  const float* be2   = (const float*)d_in[6];
  const float* aw1   = (const float*)d_in[7];
  const float* aw1b  = (const float*)d_in[8];
  const float* aw2   = (const float*)d_in[9];
  const float* aw2b  = (const float*)d_in[10];
  const float* ab1   = (const float*)d_in[11];
  const float* ab1b  = (const float*)d_in[12];
  const float* ab2   = (const float*)d_in[13];
  const float* ab2b  = (const float*)d_in[14];
  const float* cw1   = (const float*)d_in[15];
  const float* cw1b  = (const float*)d_in[16];
  const float* cw2   = (const float*)d_in[17];
  const float* cw2b  = (const float*)d_in[18];
  const float* cb1   = (const float*)d_in[19];
  const float* cb1b  = (const float*)d_in[20];
  const float* cb2   = (const float*)d_in[21];
  const float* cb2b  = (const float*)d_in[22];
  float* out = (float*)d_out_v;
  float* ws_ha = (float*)d_ws;                       // [256][128] f32
  float* ws_hc = ws_ha + 256 * 128;                  // [256][128] f32
  unsigned short* ws_obs = (unsigned short*)(ws_hc + 256 * 128);  // [256][1024] bf16

  kprep<<<256, 128, 0, stream>>>(obs, task, action, we1, be1, we2, be2, aw1, aw1b,
                                 ab1, ab1b, ab2, ab2b, cw1, cw1b, cb1, cb1b,
                                 cb2, cb2b, ws_ha, ws_hc, ws_obs, out);
  khyper<<<513, 512, 0, stream>>>(ws_obs, aw2, aw2b, cw2, cw2b, ws_ha, ws_hc, out);
  kfinal<<<256, 256, 0, stream>>>(action, out);
}

// Round 4
// 166.608 us; speedup vs baseline: 2.0662x; 1.4242x over previous
//
#include <hip/hip_runtime.h>
#include <hip/hip_bf16.h>

// Problem constants
#define B_SZ 256
#define SDIM 1024
#define ADIM 512

// khyper tile: 256-thread blocks, N-half = 80 rows, K-half = 512
#define BK 128
#define KSPLIT 2
#define KHALF (SDIM / KSPLIT)          // 512
#define NCHUNK (KHALF / BK)            // 4
#define ROWS 80                        // B-rows per block (half of 160)
#define PADB 136                       // ushort per LDS row (272B stride -> 2-way banks)
#define NSLOT 10                       // 80 rows * 32 float4 / 256 threads

typedef __attribute__((ext_vector_type(8))) short bf16x8;
typedef __attribute__((ext_vector_type(4))) float f32x4;

__device__ __forceinline__ unsigned short f2bf(float x) {
  union { float f; unsigned u; } v; v.f = x;
  unsigned r = v.u + 0x7FFFu + ((v.u >> 16) & 1u);   // round-to-nearest-even
  return (unsigned short)(r >> 16);
}

// ---------------- Kernel 1: small MLPs + obs->bf16 staging ----------------
__global__ __launch_bounds__(128) void kprep(
    const float* __restrict__ obs,
    const float* __restrict__ task, const int* __restrict__ action,
    const float* __restrict__ we1, const float* __restrict__ be1,
    const float* __restrict__ we2, const float* __restrict__ be2,
    const float* __restrict__ aw1, const float* __restrict__ aw1b,
    const float* __restrict__ ab1, const float* __restrict__ ab1b,
    const float* __restrict__ ab2, const float* __restrict__ ab2b,
    const float* __restrict__ cw1, const float* __restrict__ cw1b,
    const float* __restrict__ cb1, const float* __restrict__ cb1b,
    const float* __restrict__ cb2, const float* __restrict__ cb2b,
    float* __restrict__ ws_ha, float* __restrict__ ws_hc,
    unsigned short* __restrict__ ws_obs,
    float* __restrict__ out)
{
  const int b = blockIdx.x, t = threadIdx.x;
  __shared__ float s_task[64], s_t1[64], s_z[64], s_hb[128], s_red[128];

  // obs row b -> bf16 into ws_obs
  {
    const float4* orow = (const float4*)(obs + (size_t)b * SDIM);
    ushort4* wrow = (ushort4*)(ws_obs + (size_t)b * SDIM);
#pragma unroll
    for (int i = 0; i < 2; ++i) {
      const int idx = t + i * 128;
      float4 v = orow[idx];
      ushort4 u;
      u.x = f2bf(v.x); u.y = f2bf(v.y); u.z = f2bf(v.z); u.w = f2bf(v.w);
      wrow[idx] = u;
    }
  }

  if (t < 64) s_task[t] = task[b * 64 + t];
  __syncthreads();
  if (t < 64) {
    float a = be1[t];
    for (int e = 0; e < 64; ++e) a += s_task[e] * we1[e * 64 + t];
    s_t1[t] = fmaxf(a, 0.0f);
  }
  __syncthreads();
  if (t < 64) {
    float a = be2[t];
    for (int e = 0; e < 64; ++e) a += s_t1[e] * we2[e * 64 + t];
    s_z[t] = fmaxf(a, 0.0f);
  }
  __syncthreads();
  {
    float a1 = aw1b[t], a2 = ab1b[t], a3 = cw1b[t], a4 = cb1b[t];
    for (int e = 0; e < 64; ++e) {
      const float zv = s_z[e];
      a1 += zv * aw1[e * 128 + t];
      a2 += zv * ab1[e * 128 + t];
      a3 += zv * cw1[e * 128 + t];
      a4 += zv * cb1[e * 128 + t];
    }
    ws_ha[b * 128 + t] = fmaxf(a1, 0.0f);
    s_hb[t] = fmaxf(a2, 0.0f);
    ws_hc[b * 128 + t] = fmaxf(a3, 0.0f);
    s_red[t] = fmaxf(a4, 0.0f) * cb2[t];   // cb2 is [128,1]
  }
  __syncthreads();
  // ba -> staged into d_out logits slots (khyper atomically accumulates on top)
  for (int o = t; o < ADIM; o += 128) {
    float a = ab2b[o];
    for (int h = 0; h < 128; ++h) a += s_hb[h] * ab2[h * ADIM + o];
    out[b * ADIM + o] = a;
  }
  // bv reduction
  for (int s = 64; s > 0; s >>= 1) {
    __syncthreads();
    if (t < s) s_red[t] += s_red[t + s];
  }
  if (t == 0) {
    out[131840 + b] = s_red[0] + cb2b[0];      // partial v (bv); critic blocks add rest
    out[131072 + b] = (float)action[b];        // action as float
  }
}

// ---------------- Kernel 2: hypernet heavy GEMM + h-reduction ----------------
// 256-thread blocks, 2/CU. Each block: M=256 (all b) x 80 B-rows x K=512.
// Reg-staged f32->bf16 LDS (40 VGPR, no spill), raw barriers (no vmcnt drain).
__global__ __launch_bounds__(256, 2) void khyper(
    const unsigned short* __restrict__ ws_obs,
    const float* __restrict__ aw2, const float* __restrict__ aw2b,
    const float* __restrict__ cw2, const float* __restrict__ cw2b,
    const float* __restrict__ ws_ha, const float* __restrict__ ws_hc,
    float* __restrict__ d_out)
{
  __shared__ unsigned short B_lds[ROWS * PADB];   // 21760 B
  __shared__ float logits_buf[B_SZ];

  const int tid = threadIdx.x;
  const int blk = blockIdx.x;
  const int kh   = blk & 1;            // K-half
  const int half = (blk >> 1) & 1;     // N-half (rows 0-79 / 80-159)
  const int col  = blk >> 2;           // 0..512 (512 = critic)
  const bool critic = (col == ADIM);
  const float* haW = critic ? ws_hc : ws_ha;
  const float* Wbase = critic ? cw2 : (aw2 + (size_t)col * SDIM);
  const size_t wstride = critic ? (size_t)SDIM : (size_t)ADIM * SDIM;
  const float* Bbias = critic ? cw2b : (aw2b + (size_t)col * SDIM);
  const int kbase = kh * KHALF;

  // Staging addressing: slot i covers row lr0+8i, 16B col c4*4
  const int lr0 = tid >> 5;            // 0..7
  const int c4  = tid & 31;            // 0..31 (x4 floats)
  const int g0  = half * ROWS + lr0;   // global B-row of slot 0
  const float* src0 = Wbase + (size_t)g0 * wstride + c4 * 4 + kbase;
  const size_t off8 = (size_t)8 * wstride;
  const float* biassrc = Bbias + c4 * 4 + kbase;
  const int soff0 = lr0 * PADB + c4 * 4;   // ushort units

  const int lane = tid & 63;
  const int wv = tid >> 6;             // 0..3 = M-group
  const int mbase = wv * 64;
  const int lrow = lane & 15;
  const int lk8 = (lane >> 4) * 8;

  const unsigned short* pA[4];
#pragma unroll
  for (int mf = 0; mf < 4; ++mf)
    pA[mf] = ws_obs + (size_t)(mbase + mf * 16 + lrow) * SDIM + kbase + lk8;

  f32x4 acc[4][5];
#pragma unroll
  for (int mf = 0; mf < 4; ++mf)
#pragma unroll
    for (int nf = 0; nf < 5; ++nf) acc[mf][nf] = (f32x4)(0.0f);

  float4 sreg[NSLOT];

  auto LOAD = [&](int c) {
    const int k0 = c * BK;
#pragma unroll
    for (int i = 0; i < NSLOT; ++i) {
      const int g = g0 + 8 * i;
      float4 v; v.x = 0.f; v.y = 0.f; v.z = 0.f; v.w = 0.f;
      if (g < 128)       v = *(const float4*)(src0 + (size_t)i * off8 + k0);
      else if (g == 128) v = *(const float4*)(biassrc + k0);
      sreg[i] = v;
    }
  };

  auto WRITE = [&]() {
#pragma unroll
    for (int i = 0; i < NSLOT; ++i) {
      ushort4 p;
      p.x = f2bf(sreg[i].x); p.y = f2bf(sreg[i].y);
      p.z = f2bf(sreg[i].z); p.w = f2bf(sreg[i].w);
      *(ushort4*)(&B_lds[soff0 + i * 8 * PADB]) = p;
    }
  };

  auto COMPUTE = [&](int c) {
    const int kg = c * BK;
#pragma unroll
    for (int kk = 0; kk < BK / 32; ++kk) {
      bf16x8 af[4];
#pragma unroll
      for (int mf = 0; mf < 4; ++mf)
        af[mf] = *(const bf16x8*)(pA[mf] + kg + kk * 32);
      bf16x8 bfr[5];
#pragma unroll
      for (int nf = 0; nf < 5; ++nf)
        bfr[nf] = *(const bf16x8*)(&B_lds[(nf * 16 + lrow) * PADB + kk * 32 + lk8]);
#pragma unroll
      for (int mf = 0; mf < 4; ++mf)
#pragma unroll
        for (int nf = 0; nf < 5; ++nf)
          acc[mf][nf] = __builtin_amdgcn_mfma_f32_16x16x32_bf16(af[mf], bfr[nf], acc[mf][nf], 0, 0, 0);
    }
  };

  const int rot = blk & 3;             // chunk-order rotation (channel desync)
  LOAD(rot);
#pragma unroll 1
  for (int c = 0; c < NCHUNK; ++c) {
    const int ce = (c + rot) & 3;
    WRITE();                                        // waits sreg (vmcnt), cvt, ds_write
    asm volatile("s_waitcnt lgkmcnt(0)" ::: "memory");
    __builtin_amdgcn_sched_barrier(0);
    __builtin_amdgcn_s_barrier();                   // raw: no vmcnt drain
    if (c + 1 < NCHUNK) LOAD((c + 1 + rot) & 3);    // next chunk in flight
    COMPUTE(ce);
    __builtin_amdgcn_sched_barrier(0);
    __builtin_amdgcn_s_barrier();                   // readers done before next WRITE
  }

  // Epilogue: partial logits[b] = sum_{h in this block} weight(h) * G[b,h]
  if (tid < B_SZ) logits_buf[tid] = 0.0f;
  __syncthreads();

  float val[4][4];
#pragma unroll
  for (int mf = 0; mf < 4; ++mf)
#pragma unroll
    for (int r = 0; r < 4; ++r) val[mf][r] = 0.0f;

#pragma unroll
  for (int nf = 0; nf < 5; ++nf) {
    const int hidx = half * ROWS + nf * 16 + lrow;
    if (hidx < 128) {
#pragma unroll
      for (int mf = 0; mf < 4; ++mf) {
        const int m0 = mbase + mf * 16 + ((lane >> 4) << 2);
#pragma unroll
        for (int r = 0; r < 4; ++r)
          val[mf][r] += haW[(m0 + r) * 128 + hidx] * acc[mf][nf][r];
      }
    } else if (hidx == 128) {   // bias row: weight 1
#pragma unroll
      for (int mf = 0; mf < 4; ++mf)
#pragma unroll
        for (int r = 0; r < 4; ++r) val[mf][r] += acc[mf][nf][r];
    }
  }

#pragma unroll
  for (int mf = 0; mf < 4; ++mf)
#pragma unroll
    for (int r = 0; r < 4; ++r) {
      float v = val[mf][r];
      v += __shfl_xor(v, 1, 64);
      v += __shfl_xor(v, 2, 64);
      v += __shfl_xor(v, 4, 64);
      v += __shfl_xor(v, 8, 64);
      val[mf][r] = v;
    }
  if ((lane & 15) == 0) {
#pragma unroll
    for (int mf = 0; mf < 4; ++mf)
#pragma unroll
      for (int r = 0; r < 4; ++r)
        atomicAdd(&logits_buf[mbase + mf * 16 + ((lane >> 4) << 2) + r], val[mf][r]);
  }
  __syncthreads();

  if (tid < B_SZ) {
    if (!critic) atomicAdd(&d_out[(size_t)tid * ADIM + col], logits_buf[tid]);
    else         atomicAdd(&d_out[131840 + tid], logits_buf[tid]);
  }
}

// ---------------- Kernel 3: log_softmax / entropy / log_prob ----------------
__global__ __launch_bounds__(256) void kfinal(const int* __restrict__ action,
                                              float* __restrict__ d_out)
{
  const int b = blockIdx.x, t = threadIdx.x;
  const float* lrow = d_out + (size_t)b * ADIM;
  __shared__ float sM[4], sS[4], sT[4];

  const float x0 = lrow[t], x1 = lrow[t + 256];
  float m = fmaxf(x0, x1);
#pragma unroll
  for (int s = 1; s < 64; s <<= 1) m = fmaxf(m, __shfl_xor(m, s, 64));
  const int wv = t >> 6, ln = t & 63;
  if (ln == 0) sM[wv] = m;
  __syncthreads();
  m = fmaxf(fmaxf(sM[0], sM[1]), fmaxf(sM[2], sM[3]));

  const float d0 = x0 - m, d1 = x1 - m;
  const float e0 = expf(d0), e1 = expf(d1);
  float s1 = e0 + e1;
  float s2 = e0 * d0 + e1 * d1;
#pragma unroll
  for (int s = 1; s < 64; s <<= 1) {
    s1 += __shfl_xor(s1, s, 64);
    s2 += __shfl_xor(s2, s, 64);
  }
  if (ln == 0) { sS[wv] = s1; sT[wv] = s2; }
  __syncthreads();
  if (t == 0) {
    const float S = sS[0] + sS[1] + sS[2] + sS[3];
    const float T = sT[0] + sT[1] + sT[2] + sT[3];
    const float lnS = logf(S);
    const int a = action[b];
    d_out[131328 + b] = (lrow[a] - m) - lnS;   // log_prob
    d_out[131584 + b] = lnS - T / S;           // entropy
  }
}

extern "C" void kernel_launch(void* const* d_in, const int* in_sizes, int n_in,
                              void* d_out_v, int out_size, void* d_ws, size_t ws_size,
                              hipStream_t stream) {
  const float* obs   = (const float*)d_in[0];
  const float* task  = (const float*)d_in[1];
  const int*   action= (const int*)  d_in[2];
  const float* we1   = (const float*)d_in[3];
  const float* be1   = (const float*)d_in[4];
  const float* we2   = (const float*)d_in[5];
  const float* be2   = (const float*)d_in[6];
  const float* aw1   = (const float*)d_in[7];
  const float* aw1b  = (const float*)d_in[8];
  const float* aw2   = (const float*)d_in[9];
  const float* aw2b  = (const float*)d_in[10];
  const float* ab1   = (const float*)d_in[11];
  const float* ab1b  = (const float*)d_in[12];
  const float* ab2   = (const float*)d_in[13];
  const float* ab2b  = (const float*)d_in[14];
  const float* cw1   = (const float*)d_in[15];
  const float* cw1b  = (const float*)d_in[16];
  const float* cw2   = (const float*)d_in[17];
  const float* cw2b  = (const float*)d_in[18];
  const float* cb1   = (const float*)d_in[19];
  const float* cb1b  = (const float*)d_in[20];
  const float* cb2   = (const float*)d_in[21];
  const float* cb2b  = (const float*)d_in[22];
  float* out = (float*)d_out_v;
  float* ws_ha = (float*)d_ws;                       // [256][128] f32
  float* ws_hc = ws_ha + 256 * 128;                  // [256][128] f32
  unsigned short* ws_obs = (unsigned short*)(ws_hc + 256 * 128);  // [256][1024] bf16

  kprep<<<256, 128, 0, stream>>>(obs, task, action, we1, be1, we2, be2, aw1, aw1b,
                                 ab1, ab1b, ab2, ab2b, cw1, cw1b, cb1, cb1b,
                                 cb2, cb2b, ws_ha, ws_hc, ws_obs, out);
  // grid: 513 cols (512 actor + critic) x 2 N-halves x 2 K-halves
  khyper<<<513 * 4, 256, 0, stream>>>(ws_obs, aw2, aw2b, cw2, cw2b, ws_ha, ws_hc, out);
  kfinal<<<256, 256, 0, stream>>>(action, out);
}